// Round 5
// baseline (53052.289 us; speedup 1.0000x reference)
//
#include <hip/hip_runtime.h>
#include <math.h>

// LSTM_11089605558768: T=16384 sequential steps, H=512, IN=32, OUT=1.
// Persistent scan, 32 worker wgs x 256 threads, weights resident in regs
// (136 floats/thread = 64x544 slice per wg, [W_hh | W_ih] folded).
//
// R5: hardware-verified XCD colocation with graceful degradation.
//  - 256 blocks. tid0 reads HW_REG_XCC_ID (HW-verified on gfx950). Blocks on
//    XCD 0 claim the 32 worker slots. Grid rendezvous (arrival counter): last
//    arriver decides FAST (all 32 slots on XCD 0) or SLOW (fill remaining
//    slots by arrival order).
//  - FAST: polls are sc0 loads (served by the shared XCD-0 L2, ~250 cyc RT);
//    every 16th spin refreshes from LLC (sc0 sc1) as a safety net. Publish =
//    sc0+sc1 store (LLC mirror, guarantees progress under ANY placement)
//    then sc0 store (fresh line in local L2). Identical payloads -> order
//    irrelevant. Wrong-FAST can only cost speed, never correctness.
//  - SLOW: exactly the proven R2 protocol: sc0+sc1 polls and stores (LLC),
//    no cacheable stale-line spinning (R4's failure mode).
//  - R3-crash hardening: d_ws use is guarded by ws_size; if ws_size cannot
//    hold pub+ctl, a fallback kernel (32 blocks, SLOW protocol, 8192 B) runs.

#define T_STEPS 16384
#define IN_DIM  32
#define H_DIM   512
#define SLOTS   32      // worker workgroups
#define GRID    256     // launched blocks for the claiming variant
#define H_SLICE 16      // H_DIM / SLOTS
#define KTOT    544     // H_DIM + IN_DIM
#define CHUNK   136     // KTOT / 4 waves

typedef unsigned int uint32x4 __attribute__((ext_vector_type(4)));

__device__ __forceinline__ float fast_sigmoid(float v) {
  return 1.0f / (1.0f + __expf(-v));
}
__device__ __forceinline__ float fast_tanh(float v) {
  return 2.0f / (1.0f + __expf(-2.0f * v)) - 1.0f;  // 2*sigmoid(2x)-1
}

// --- packet I/O ------------------------------------------------------------
__device__ __forceinline__ void store_pkt_llc(unsigned long long* p,
                                              unsigned long long v) {
  asm volatile("global_store_dwordx2 %0, %1, off sc0 sc1"
               :: "v"(p), "v"(v) : "memory");
}
__device__ __forceinline__ void store_pkt_l2(unsigned long long* p,
                                             unsigned long long v) {
  asm volatile("global_store_dwordx2 %0, %1, off sc0"
               :: "v"(p), "v"(v) : "memory");
}
__device__ __forceinline__ uint32x4 load_pkt2_l2(const unsigned long long* p) {
  uint32x4 r;
  asm volatile("global_load_dwordx4 %0, %1, off sc0\n\ts_waitcnt vmcnt(0)"
               : "=&v"(r) : "v"(p) : "memory");
  return r;
}
__device__ __forceinline__ uint32x4 load_pkt2_llc(const unsigned long long* p) {
  uint32x4 r;
  asm volatile("global_load_dwordx4 %0, %1, off sc0 sc1\n\ts_waitcnt vmcnt(0)"
               : "=&v"(r) : "v"(p) : "memory");
  return r;
}

// MODE: 1 = FAST (XCD-L2 polls + LLC refresh/mirror), 0 = SLOW (LLC only).
template <int MODE>
__device__ __forceinline__ void poll_pkts(const unsigned long long* p,
                                          unsigned int tg,
                                          float* d0, float* d1) {
  unsigned int spin = 0;
  for (;;) {
    uint32x4 r;
    if (MODE == 1)
      r = ((++spin & 15u) != 0u) ? load_pkt2_l2(p) : load_pkt2_llc(p);
    else
      r = load_pkt2_llc(p);
    if (r.y == tg && r.w == tg) {   // [val0, tag0, val1, tag1]
      *d0 = __uint_as_float(r.x);
      *d1 = __uint_as_float(r.z);
      return;
    }
  }
}

template <int MODE>
__device__ __forceinline__ void publish_pkt(unsigned long long* p,
                                            unsigned long long v) {
  store_pkt_llc(p, v);               // progress guarantee under any placement
  if (MODE == 1) store_pkt_l2(p, v); // fresh line in the local XCD L2
}

// --- shared scan body ------------------------------------------------------
template <int MODE>
__device__ void run_scan(const int slot,
                         const float* __restrict__ x,
                         const float* __restrict__ Wih,
                         const float* __restrict__ Whh,
                         const float* __restrict__ bih,
                         const float* __restrict__ bhh,
                         const float* __restrict__ Wlin,
                         const float* __restrict__ blin,
                         float* __restrict__ out,
                         unsigned long long* pub,
                         float* hshm, float* red) {
  const int tid = threadIdx.x;
  const int w   = tid >> 6;   // wave 0..3 -> k-chunk
  const int l   = tid & 63;   // lane -> local gate row

  // local row l: 0..15 = i, 16..31 = f, 32..47 = g, 48..63 = o
  const int R = (l >> 4) * H_DIM + slot * H_SLICE + (l & 15);

  float wreg[CHUNK];
  #pragma unroll
  for (int j = 0; j < CHUNK; ++j) {
    const int k = w * CHUNK + j;
    wreg[j] = (k < H_DIM) ? Whh[R * H_DIM + k]
                          : Wih[R * IN_DIM + (k - H_DIM)];
  }
  const float bias = (w == 0) ? (bih[R] + bhh[R]) : 0.0f;

  float c = 0.0f;  // cell state: wave 0, lanes 0..15 (h index slot*16 + l)

  const int  e0  = tid * 2;               // this thread's 2 h elements
  const bool own = ((tid >> 3) == slot);  // both elements in own slice
  if (own) { hshm[e0] = 0.0f; hshm[e0 + 1] = 0.0f; }  // h(0) = 0 shortcut

  for (int t = 0; t < T_STEPS; ++t) {
    float xv = (tid < IN_DIM) ? x[t * IN_DIM + tid] : 0.0f;

    if (!own) {
      poll_pkts<MODE>(pub + (t & 1) * H_DIM + e0, (unsigned int)t,
                      &hshm[e0], &hshm[e0 + 1]);
    }
    if (tid < IN_DIM) hshm[H_DIM + tid] = xv;
    __syncthreads();  // barrier B: h(t) + x_t staged

    const float4* hv = (const float4*)(hshm + w * CHUNK);  // 544B-aligned
    float a0 = 0.f, a1 = 0.f, a2 = 0.f, a3 = 0.f;
    #pragma unroll
    for (int q = 0; q < CHUNK / 4; ++q) {
      const float4 h4 = hv[q];  // wave-uniform broadcast read
      a0 = fmaf(wreg[4 * q + 0], h4.x, a0);
      a1 = fmaf(wreg[4 * q + 1], h4.y, a1);
      a2 = fmaf(wreg[4 * q + 2], h4.z, a2);
      a3 = fmaf(wreg[4 * q + 3], h4.w, a3);
    }
    red[w * 64 + l] = (a0 + a1) + (a2 + a3);
    __syncthreads();  // barrier C: partials ready

    if (w == 0) {
      const float g = bias + red[l] + red[64 + l] + red[128 + l] + red[192 + l];
      // lanes 0-15: i (sig), 16-31: f (sig), 32-47: g (tanh), 48-63: o (sig)
      const float act = (l < 32 || l >= 48) ? fast_sigmoid(g) : fast_tanh(g);
      const int j = l & 15;
      const float ig = __shfl(act, j, 64);
      const float fg = __shfl(act, j + 16, 64);
      const float gt = __shfl(act, j + 32, 64);
      const float og = __shfl(act, j + 48, 64);
      if (l < H_SLICE) {
        c = fg * c + ig * gt;
        const float h = og * fast_tanh(c);
        hshm[slot * H_SLICE + l] = h;  // own-slice shortcut for step t+1
        const unsigned long long u =
            ((unsigned long long)(unsigned int)(t + 1) << 32) |
            (unsigned long long)__float_as_uint(h);
        publish_pkt<MODE>(pub + ((t + 1) & 1) * H_DIM + slot * H_SLICE + l, u);
      }
    }
    // hshm[own]/red hazards covered by barriers B/C (disjoint index sets).
  }

  // ---- slot 0: final projection out = h(T) . Wlin + blin ----
  if (slot == 0) {
    if (!own) {
      poll_pkts<MODE>(pub + (T_STEPS & 1) * H_DIM + e0,
                      (unsigned int)T_STEPS, &hshm[e0], &hshm[e0 + 1]);
    }
    __syncthreads();
    red[tid] = hshm[e0] * Wlin[e0] + hshm[e0 + 1] * Wlin[e0 + 1];
    __syncthreads();
    if (w == 0) {
      float s = red[l] + red[64 + l] + red[128 + l] + red[192 + l];
      #pragma unroll
      for (int off = 32; off > 0; off >>= 1) s += __shfl_down(s, off, 64);
      if (l == 0) out[0] = s + blin[0];
    }
  }
}

// --- claiming kernel (preferred) -------------------------------------------
__launch_bounds__(256, 1)
__global__ void lstm_claim_kernel(
    const float* __restrict__ x, const float* __restrict__ Wih,
    const float* __restrict__ Whh, const float* __restrict__ bih,
    const float* __restrict__ bhh, const float* __restrict__ Wlin,
    const float* __restrict__ blin, float* __restrict__ out,
    unsigned long long* pub,   // [2][512] packets
    unsigned int* ctl)         // [0]=fast_claims [1]=arrived [2]=state
                               // [3]=slow_claims [4]=base
{
  __shared__ __align__(16) float hshm[KTOT];
  __shared__ float red[256];
  __shared__ int s_slot, s_mode;

  if (threadIdx.x == 0) {
    unsigned int xcc;
    asm volatile("s_getreg_b32 %0, hwreg(HW_REG_XCC_ID)" : "=s"(xcc));
    xcc &= 0xFu;
    int slot = -1;
    if (xcc == 0u) {
      unsigned int r = __hip_atomic_fetch_add(&ctl[0], 1u, __ATOMIC_ACQ_REL,
                                              __HIP_MEMORY_SCOPE_AGENT);
      if (r < SLOTS) slot = (int)r;
    }
    unsigned int a = __hip_atomic_fetch_add(&ctl[1], 1u, __ATOMIC_ACQ_REL,
                                            __HIP_MEMORY_SCOPE_AGENT);
    if (a == GRID - 1) {  // last arriver decides
      unsigned int n0 = __hip_atomic_load(&ctl[0], __ATOMIC_ACQUIRE,
                                          __HIP_MEMORY_SCOPE_AGENT);
      unsigned int base = n0 < SLOTS ? n0 : SLOTS;
      __hip_atomic_store(&ctl[4], base, __ATOMIC_RELEASE,
                         __HIP_MEMORY_SCOPE_AGENT);
      __hip_atomic_store(&ctl[2], (base == SLOTS) ? 1u : 2u, __ATOMIC_RELEASE,
                         __HIP_MEMORY_SCOPE_AGENT);
    }
    unsigned int st;
    do {
      st = __hip_atomic_load(&ctl[2], __ATOMIC_ACQUIRE,
                             __HIP_MEMORY_SCOPE_AGENT);
    } while (st == 0u);
    if (st == 2u && slot < 0) {  // SLOW: fill remaining slots, any XCD
      unsigned int base = __hip_atomic_load(&ctl[4], __ATOMIC_ACQUIRE,
                                            __HIP_MEMORY_SCOPE_AGENT);
      unsigned int r = __hip_atomic_fetch_add(&ctl[3], 1u, __ATOMIC_ACQ_REL,
                                              __HIP_MEMORY_SCOPE_AGENT);
      if (base + r < SLOTS) slot = (int)(base + r);
    }
    s_slot = slot;
    s_mode = (int)st;
  }
  __syncthreads();
  const int slot = s_slot;
  if (slot < 0) return;  // non-worker block exits, frees its CU

  if (s_mode == 1)
    run_scan<1>(slot, x, Wih, Whh, bih, bhh, Wlin, blin, out, pub, hshm, red);
  else
    run_scan<0>(slot, x, Wih, Whh, bih, bhh, Wlin, blin, out, pub, hshm, red);
}

// --- fallback kernel (d_ws too small for ctl): proven R2 structure ---------
__launch_bounds__(256, 1)
__global__ void lstm_plain_kernel(
    const float* __restrict__ x, const float* __restrict__ Wih,
    const float* __restrict__ Whh, const float* __restrict__ bih,
    const float* __restrict__ bhh, const float* __restrict__ Wlin,
    const float* __restrict__ blin, float* __restrict__ out,
    unsigned long long* pub) {
  __shared__ __align__(16) float hshm[KTOT];
  __shared__ float red[256];
  run_scan<0>(blockIdx.x, x, Wih, Whh, bih, bhh, Wlin, blin, out, pub,
              hshm, red);
}

extern "C" void kernel_launch(void* const* d_in, const int* in_sizes, int n_in,
                              void* d_out, int out_size, void* d_ws, size_t ws_size,
                              hipStream_t stream) {
  const float* x    = (const float*)d_in[0];
  const float* Wih  = (const float*)d_in[1];
  const float* Whh  = (const float*)d_in[2];
  const float* bih  = (const float*)d_in[3];
  const float* bhh  = (const float*)d_in[4];
  const float* Wlin = (const float*)d_in[5];
  const float* blin = (const float*)d_in[6];
  float* out = (float*)d_out;

  unsigned long long* pub = (unsigned long long*)d_ws;  // [2][512] u64 = 8192B
  unsigned int* ctl = (unsigned int*)((char*)d_ws + 8192);  // 5 u32

  if (ws_size >= 8192 + 64) {
    // d_ws re-poisoned 0xAA each timed call: zero pub (tag0 == h(0)=0) + ctl.
    hipMemsetAsync(d_ws, 0, 8192 + 64, stream);
    hipLaunchKernelGGL(lstm_claim_kernel, dim3(GRID), dim3(256), 0, stream,
                       x, Wih, Whh, bih, bhh, Wlin, blin, out, pub, ctl);
  } else {
    hipMemsetAsync(d_ws, 0, 8192, stream);
    hipLaunchKernelGGL(lstm_plain_kernel, dim3(SLOTS), dim3(256), 0, stream,
                       x, Wih, Whh, bih, bhh, Wlin, blin, out, pub);
  }
}

// Round 6
// 28600.790 us; speedup vs baseline: 1.8549x; 1.8549x over previous
//
#include <hip/hip_runtime.h>
#include <hip/hip_fp16.h>
#include <math.h>

// LSTM_11089605558768: T=16384 sequential steps, H=512, IN=32, OUT=1.
// Persistent scan, 32 worker wgs x 256 threads; each wg owns 16 h-elements
// (64 gate rows x 544 k, [W_hh | W_ih] folded).
//
// R6 (base = proven R2 LLC exchange; XCD-L2 experiments R4/R5 falsified):
//  1. Weights PINNED in VGPRs via opaque asm identity (R2-R5 counters showed
//     VGPR_Count=92 < 136 -> compiler was re-streaming weights from L2 every
//     step inside the serial FMA leg).
//  2. 4-byte self-validating packets: tag16<<16 | fp16(h). One dwordx4 polls
//     4 packets; 128 polling threads instead of 248; zeroed buffer encodes
//     (tag=0, h=0) = initial state. All exchange ops sc0+sc1 (LLC, the only
//     HW-verified coherent path).
//  3. All-lane activation epilogue; plain 32-block launch (no claim logic).

#define T_STEPS 16384
#define IN_DIM  32
#define H_DIM   512
#define SLOTS   32
#define H_SLICE 16      // H_DIM / SLOTS
#define KTOT    544     // H_DIM + IN_DIM
#define CHUNK   136     // KTOT / 4 waves

typedef unsigned int uint32x4 __attribute__((ext_vector_type(4)));

__device__ __forceinline__ float fast_sigmoid(float v) {
  return 1.0f / (1.0f + __expf(-v));
}
__device__ __forceinline__ float fast_tanh(float v) {
  return 2.0f / (1.0f + __expf(-2.0f * v)) - 1.0f;  // 2*sigmoid(2x)-1
}

// --- packet I/O (always LLC-coherent: sc0 sc1) -----------------------------
__device__ __forceinline__ void store_pkt(unsigned int* p, unsigned int v) {
  asm volatile("global_store_dword %0, %1, off sc0 sc1"
               :: "v"(p), "v"(v) : "memory");
}
__device__ __forceinline__ uint32x4 load_pkt4(const unsigned int* p) {
  uint32x4 r;
  asm volatile("global_load_dwordx4 %0, %1, off sc0 sc1\n\ts_waitcnt vmcnt(0)"
               : "=&v"(r) : "v"(p) : "memory");
  return r;
}

__launch_bounds__(256, 1)
__global__ void lstm_scan_kernel(
    const float* __restrict__ x,     // [T, 32]
    const float* __restrict__ Wih,   // [2048, 32]
    const float* __restrict__ Whh,   // [2048, 512]
    const float* __restrict__ bih,   // [2048]
    const float* __restrict__ bhh,   // [2048]
    const float* __restrict__ Wlin,  // [512]
    const float* __restrict__ blin,  // [1]
    float* __restrict__ out,         // [1]
    unsigned int* pub)               // [2][512] 4B packets (d_ws)
{
  const int slot = blockIdx.x;       // 0..31
  const int tid  = threadIdx.x;
  const int w    = tid >> 6;   // wave 0..3 -> k-chunk
  const int l    = tid & 63;   // lane -> local gate row

  __shared__ __align__(16) float hshm[KTOT];  // [0,512)=h(t), [512,544)=x_t
  __shared__ float red[256];                  // per-wave partials

  // local row l: 0..15 = i, 16..31 = f, 32..47 = g, 48..63 = o
  const int R = (l >> 4) * H_DIM + slot * H_SLICE + (l & 15);

  // Persistent weight slice -> registers, then PIN with opaque asm identity
  // so the compiler cannot rematerialize the loads inside the t-loop.
  float wreg[CHUNK];
  #pragma unroll
  for (int j = 0; j < CHUNK; ++j) {
    const int k = w * CHUNK + j;
    wreg[j] = (k < H_DIM) ? Whh[R * H_DIM + k]
                          : Wih[R * IN_DIM + (k - H_DIM)];
  }
  #pragma unroll
  for (int j = 0; j < CHUNK; ++j)
    asm volatile("v_mov_b32 %0, %0" : "+v"(wreg[j]));

  const float bias = (w == 0) ? (bih[R] + bhh[R]) : 0.0f;

  float c = 0.0f;  // cell state: wave 0, lanes 0..15 (h index slot*16 + l)

  // Polling assignment: tid<128 polls packets [4*tid, 4*tid+4); the group
  // equal to own slice is skipped (wave-0 epilogue provides it in fp32).
  const bool poller = (tid < 128) && ((tid >> 2) != slot);
  if (tid < H_SLICE) hshm[slot * H_SLICE + tid] = 0.0f;  // h(0) own slice

  for (int t = 0; t < T_STEPS; ++t) {
    // x_t load overlaps the poll (independent)
    float xv = (tid < IN_DIM) ? x[t * IN_DIM + tid] : 0.0f;

    // ---- gather h(t): poll 4 self-validating packets per thread ----
    if (poller) {
      const unsigned int* p = pub + (t & 1) * H_DIM + tid * 4;
      const unsigned int tg = (unsigned int)t & 0xFFFFu;
      uint32x4 r;
      for (;;) {
        r = load_pkt4(p);
        if ((r.x >> 16) == tg && (r.y >> 16) == tg &&
            (r.z >> 16) == tg && (r.w >> 16) == tg) break;
      }
      float4 hv4;
      hv4.x = __half2float(__ushort_as_half((unsigned short)(r.x & 0xFFFFu)));
      hv4.y = __half2float(__ushort_as_half((unsigned short)(r.y & 0xFFFFu)));
      hv4.z = __half2float(__ushort_as_half((unsigned short)(r.z & 0xFFFFu)));
      hv4.w = __half2float(__ushort_as_half((unsigned short)(r.w & 0xFFFFu)));
      *(float4*)(hshm + tid * 4) = hv4;
    }
    if (tid < IN_DIM) hshm[H_DIM + tid] = xv;
    __syncthreads();  // barrier B: h(t) + x_t staged

    // ---- matvec: thread (w,l) covers row l, k in [w*136, w*136+136) ----
    const float4* hv = (const float4*)(hshm + w * CHUNK);  // 544B-aligned
    float a0 = 0.f, a1 = 0.f, a2 = 0.f, a3 = 0.f;
    #pragma unroll
    for (int q = 0; q < CHUNK / 4; ++q) {
      const float4 h4 = hv[q];  // wave-uniform broadcast read
      a0 = fmaf(wreg[4 * q + 0], h4.x, a0);
      a1 = fmaf(wreg[4 * q + 1], h4.y, a1);
      a2 = fmaf(wreg[4 * q + 2], h4.z, a2);
      a3 = fmaf(wreg[4 * q + 3], h4.w, a3);
    }
    red[w * 64 + l] = (a0 + a1) + (a2 + a3);
    __syncthreads();  // barrier C: partials ready

    // ---- wave 0: activate (all 64 lanes in parallel), update, publish ----
    if (w == 0) {
      const float g = bias + red[l] + red[64 + l] + red[128 + l] + red[192 + l];
      // lanes 0-15: i (sig), 16-31: f (sig), 32-47: g (tanh), 48-63: o (sig)
      const float act = (l < 32 || l >= 48) ? fast_sigmoid(g) : fast_tanh(g);
      const int j = l & 15;
      const float ig = __shfl(act, j, 64);
      const float fg = __shfl(act, j + 16, 64);
      const float gt = __shfl(act, j + 32, 64);
      const float og = __shfl(act, j + 48, 64);
      if (l < H_SLICE) {
        c = fg * c + ig * gt;
        const float h = og * fast_tanh(c);
        hshm[slot * H_SLICE + l] = h;  // own-slice shortcut (fp32)
        const unsigned int pkt =
            (((unsigned int)(t + 1) & 0xFFFFu) << 16) |
            (unsigned int)__half_as_ushort(__float2half_rn(h));
        store_pkt(pub + ((t + 1) & 1) * H_DIM + slot * H_SLICE + l, pkt);
      }
    }
    // hshm/red hazards covered by barriers B/C (disjoint index sets).
  }

  // ---- slot 0: final projection out = h(T) . Wlin + blin ----
  if (slot == 0) {
    if (poller) {  // gather h(T) (parity T&1 == 0); own slice already fp32
      const unsigned int* p = pub + (T_STEPS & 1) * H_DIM + tid * 4;
      const unsigned int tg = (unsigned int)T_STEPS & 0xFFFFu;
      uint32x4 r;
      for (;;) {
        r = load_pkt4(p);
        if ((r.x >> 16) == tg && (r.y >> 16) == tg &&
            (r.z >> 16) == tg && (r.w >> 16) == tg) break;
      }
      float4 hv4;
      hv4.x = __half2float(__ushort_as_half((unsigned short)(r.x & 0xFFFFu)));
      hv4.y = __half2float(__ushort_as_half((unsigned short)(r.y & 0xFFFFu)));
      hv4.z = __half2float(__ushort_as_half((unsigned short)(r.z & 0xFFFFu)));
      hv4.w = __half2float(__ushort_as_half((unsigned short)(r.w & 0xFFFFu)));
      *(float4*)(hshm + tid * 4) = hv4;
    }
    __syncthreads();
    red[tid] = hshm[2 * tid] * Wlin[2 * tid] +
               hshm[2 * tid + 1] * Wlin[2 * tid + 1];
    __syncthreads();
    if (w == 0) {
      float s = red[l] + red[64 + l] + red[128 + l] + red[192 + l];
      #pragma unroll
      for (int off = 32; off > 0; off >>= 1) s += __shfl_down(s, off, 64);
      if (l == 0) out[0] = s + blin[0];
    }
  }
}

extern "C" void kernel_launch(void* const* d_in, const int* in_sizes, int n_in,
                              void* d_out, int out_size, void* d_ws, size_t ws_size,
                              hipStream_t stream) {
  const float* x    = (const float*)d_in[0];
  const float* Wih  = (const float*)d_in[1];
  const float* Whh  = (const float*)d_in[2];
  const float* bih  = (const float*)d_in[3];
  const float* bhh  = (const float*)d_in[4];
  const float* Wlin = (const float*)d_in[5];
  const float* blin = (const float*)d_in[6];
  float* out = (float*)d_out;

  unsigned int* pub = (unsigned int*)d_ws;  // [2][512] u32 = 4096 B

  // d_ws re-poisoned 0xAA before every timed call; zeroed pub encodes
  // (tag=0, h=0) == the initial hidden state.
  hipMemsetAsync(d_ws, 0, 4096, stream);
  hipLaunchKernelGGL(lstm_scan_kernel, dim3(SLOTS), dim3(256), 0, stream,
                     x, Wih, Whh, bih, bhh, Wlin, blin, out, pub);
}